// Round 1
// baseline (185.235 us; speedup 1.0000x reference)
//
#include <hip/hip_runtime.h>

// AdaptiveDecayMemory: out = ((Q K^T * scale) ∘ W_decay) V Wo^T * out_scale
// B=4, T=2048, D=1024.  All GEMMs in bf16 MFMA (fp32 accum).
// Anti-causal mask (j > i) -> upper-triangular S; tile-level skip.

using u16 = unsigned short;
typedef __bf16 bf16x8 __attribute__((ext_vector_type(8)));
typedef float f32x4 __attribute__((ext_vector_type(4)));

#define BM 128
#define BN 128
#define BKK 64

__device__ inline u16 f2bf(float f) {
  unsigned u = __builtin_bit_cast(unsigned, f);
  unsigned r = (u + 0x7FFFu + ((u >> 16) & 1u)) >> 16;   // RNE
  return (u16)r;
}

__device__ inline void gload16(const u16* g, u16* l) {
  __builtin_amdgcn_global_load_lds(
      (const __attribute__((address_space(1))) void*)g,
      (__attribute__((address_space(3))) void*)l, 16, 0, 0);
}

__global__ void cast_f32_bf16(const float* __restrict__ in, u16* __restrict__ out, int n) {
  int i = (blockIdx.x * blockDim.x + threadIdx.x) * 4;
  if (i >= n) return;
  float4 f = *reinterpret_cast<const float4*>(in + i);
  ushort4 o;
  o.x = f2bf(f.x); o.y = f2bf(f.y); o.z = f2bf(f.z); o.w = f2bf(f.w);
  *reinterpret_cast<ushort4*>(out + i) = o;
}

// log_decay[m] = log(sigmoid(x[m,:]·Wd + bd) + 1e-8), one wave per row.
__global__ __launch_bounds__(256) void decay_kernel(const float* __restrict__ x,
    const float* __restrict__ Wd, const float* __restrict__ bd,
    float* __restrict__ ldec) {
  int row = blockIdx.x * 4 + (threadIdx.x >> 6);
  int lane = threadIdx.x & 63;
  const float4* xr = reinterpret_cast<const float4*>(x + (size_t)row * 1024);
  const float4* wd = reinterpret_cast<const float4*>(Wd);
  float s = 0.f;
  #pragma unroll
  for (int i = 0; i < 4; ++i) {
    float4 a = xr[lane + 64 * i];
    float4 b = wd[lane + 64 * i];
    s += a.x * b.x + a.y * b.y + a.z * b.z + a.w * b.w;
  }
  #pragma unroll
  for (int off = 32; off > 0; off >>= 1) s += __shfl_xor(s, off);
  if (lane == 0) {
    float logit = s + bd[0];
    float dec = 1.f / (1.f + expf(-logit));
    ldec[row] = logf(dec + 1e-8f);
  }
}

// C[m,n] = sum_k A[m,k] * B[n,k]   (both row-major, K contiguous: "BT" layout)
// EPI 0: bf16 store.  EPI 1: decay-weight epilogue -> bf16 (skips jt<it tiles).
// EPI 2: fp32 store * scale_ptr[0].
// diag=1: K-loop starts at tile it*BM (upper-triangular retrieval GEMM).
template <int EPI>
__global__ __launch_bounds__(256, 2)
void gemm_bt(const u16* __restrict__ Ab, const u16* __restrict__ Bb,
             void* __restrict__ Cv, int lda, int ldb, int ldc, int K,
             int tiles_n, int diag, const float* __restrict__ ldec,
             const float* __restrict__ scale_ptr,
             long long abs_, long long bbs_, long long cbs_, int ld_stride) {
  __shared__ __align__(16) u16 lsA[BM * BKK];
  __shared__ __align__(16) u16 lsB[BN * BKK];

  const int batch = blockIdx.y;
  const u16* A = Ab + (size_t)batch * abs_;
  const u16* B = Bb + (size_t)batch * bbs_;

  const int it = blockIdx.x / tiles_n;
  const int jt = blockIdx.x % tiles_n;
  if (EPI == 1 && jt < it) return;  // strictly lower-tri S tiles are all-zero, never read
  const int m0 = it * BM, n0 = jt * BN;

  const int tid = threadIdx.x;
  const int lane = tid & 63;
  const int w = tid >> 6;               // wave 0..3, 2x2 over the 128x128 tile
  const int wm = (w >> 1) * 64, wn = (w & 1) * 64;
  const int l15 = lane & 15, lhi = lane >> 4;

  // staging: LDS linear dest (global_load_lds), source chunk pre-swizzled so that
  // LDS slot (row r, slot s) holds global chunk (s ^ (r&7))  [rule #21]
  const int srow = lane >> 3;                 // 0..7 within the 8-row group
  const int schunk = (lane & 7) ^ srow;       // source 16B chunk

  f32x4 acc[4][4];
  #pragma unroll
  for (int i = 0; i < 4; ++i)
    #pragma unroll
    for (int j = 0; j < 4; ++j) acc[i][j] = (f32x4)0.f;

  const int kt0 = diag ? it * (BM / BKK) : 0;
  const int nkt = K / BKK;

  for (int kt = kt0; kt < nkt; ++kt) {
    const int k0 = kt * BKK;
    __syncthreads();   // previous tile's reads done before overwrite
    #pragma unroll
    for (int is = 0; is < 4; ++is) {
      int r = (is * 4 + w) * 8 + srow;
      gload16(A + (size_t)(m0 + r) * lda + (k0 + schunk * 8), &lsA[(is * 4 + w) * 512]);
    }
    #pragma unroll
    for (int is = 0; is < 4; ++is) {
      int r = (is * 4 + w) * 8 + srow;
      gload16(B + (size_t)(n0 + r) * ldb + (k0 + schunk * 8), &lsB[(is * 4 + w) * 512]);
    }
    __syncthreads();   // vmcnt(0) drain: staged data visible
    #pragma unroll
    for (int kk = 0; kk < 2; ++kk) {
      bf16x8 af[4], bv[4];
      #pragma unroll
      for (int mi = 0; mi < 4; ++mi) {
        int r = wm + mi * 16 + l15;
        int s = (kk * 4 + lhi) ^ (r & 7);
        af[mi] = *reinterpret_cast<const bf16x8*>(&lsA[r * 64 + s * 8]);
      }
      #pragma unroll
      for (int ni = 0; ni < 4; ++ni) {
        int r = wn + ni * 16 + l15;
        int s = (kk * 4 + lhi) ^ (r & 7);
        bv[ni] = *reinterpret_cast<const bf16x8*>(&lsB[r * 64 + s * 8]);
      }
      #pragma unroll
      for (int mi = 0; mi < 4; ++mi)
        #pragma unroll
        for (int ni = 0; ni < 4; ++ni)
          acc[mi][ni] = __builtin_amdgcn_mfma_f32_16x16x32_bf16(af[mi], bv[ni], acc[mi][ni], 0, 0, 0);
    }
  }

  // epilogue: lane l, reg q of frag (mi,ni) holds C[m0+wm+mi*16+lhi*4+q][n0+wn+ni*16+l15]
  if (EPI == 0) {
    u16* C = (u16*)Cv + (size_t)batch * cbs_;
    #pragma unroll
    for (int mi = 0; mi < 4; ++mi)
      #pragma unroll
      for (int q = 0; q < 4; ++q) {
        int row = m0 + wm + mi * 16 + lhi * 4 + q;
        u16* crow = C + (size_t)row * ldc + n0 + wn + l15;
        #pragma unroll
        for (int ni = 0; ni < 4; ++ni) crow[ni * 16] = f2bf(acc[mi][ni][q]);
      }
  } else if (EPI == 1) {
    u16* C = (u16*)Cv + (size_t)batch * cbs_;
    const float* ldb_ = ldec + (size_t)batch * ld_stride;
    float ldv[4];
    #pragma unroll
    for (int ni = 0; ni < 4; ++ni) ldv[ni] = ldb_[n0 + wn + ni * 16 + l15];
    const float sc = 0.03125f;  // 1/sqrt(1024)
    #pragma unroll
    for (int mi = 0; mi < 4; ++mi)
      #pragma unroll
      for (int q = 0; q < 4; ++q) {
        int row = m0 + wm + mi * 16 + lhi * 4 + q;
        u16* crow = C + (size_t)row * ldc + n0 + wn + l15;
        #pragma unroll
        for (int ni = 0; ni < 4; ++ni) {
          int col = n0 + wn + ni * 16 + l15;
          int d = col - row;
          float wgt = (d > 0) ? expf(ldv[ni] * (float)(d - 1)) : 0.f;
          crow[ni * 16] = f2bf(acc[mi][ni][q] * sc * wgt);
        }
      }
  } else {
    float* C = (float*)Cv + (size_t)batch * cbs_;
    const float sc = scale_ptr[0];
    #pragma unroll
    for (int mi = 0; mi < 4; ++mi)
      #pragma unroll
      for (int q = 0; q < 4; ++q) {
        int row = m0 + wm + mi * 16 + lhi * 4 + q;
        float* crow = C + (size_t)row * ldc + n0 + wn + l15;
        #pragma unroll
        for (int ni = 0; ni < 4; ++ni) crow[ni * 16] = acc[mi][ni][q] * sc;
      }
  }
}

extern "C" void kernel_launch(void* const* d_in, const int* in_sizes, int n_in,
                              void* d_out, int out_size, void* d_ws, size_t ws_size,
                              hipStream_t stream) {
  const float* x   = (const float*)d_in[0];
  const float* Wq  = (const float*)d_in[1];
  const float* Wk  = (const float*)d_in[2];
  const float* Wv  = (const float*)d_in[3];
  const float* Wo  = (const float*)d_in[4];
  const float* Wd  = (const float*)d_in[5];
  const float* bd  = (const float*)d_in[6];
  const float* osc = (const float*)d_in[7];
  float* out = (float*)d_out;

  // workspace layout (bytes); total ~109.1 MB
  char* ws = (char*)d_ws;
  size_t off = 0;
  u16* Xbf = (u16*)(ws + off); off += (size_t)8192 * 1024 * 2;   // 16.78 MB
  u16* Wqk = (u16*)(ws + off); off += (size_t)2048 * 1024 * 2;   //  4.19 MB (Wq rows 0-1023, Wk rows 1024-2047)
  u16* Wvb = (u16*)(ws + off); off += (size_t)1024 * 1024 * 2;
  u16* Wob = (u16*)(ws + off); off += (size_t)1024 * 1024 * 2;
  u16* VT  = (u16*)(ws + off); off += (size_t)1024 * 8192 * 2;   // 16.78 MB  V^T[d, b*2048+s]
  u16* S   = (u16*)(ws + off); off += (size_t)4 * 2048 * 2048 * 2; // 33.55 MB
  float* ldec = (float*)(ws + off); off += (size_t)8192 * 4;
  u16* QK  = (u16*)(ws + off); off += (size_t)8192 * 2048 * 2;   // 33.55 MB
  u16* R   = QK;  // alias: QK dead once S is built; R is 16.78 MB << 33.55 MB

  // 1) casts
  cast_f32_bf16<<<8192, 256, 0, stream>>>(x, Xbf, 8192 * 1024);
  cast_f32_bf16<<<1024, 256, 0, stream>>>(Wq, Wqk, 1024 * 1024);
  cast_f32_bf16<<<1024, 256, 0, stream>>>(Wk, Wqk + 1024 * 1024, 1024 * 1024);
  cast_f32_bf16<<<1024, 256, 0, stream>>>(Wv, Wvb, 1024 * 1024);
  cast_f32_bf16<<<1024, 256, 0, stream>>>(Wo, Wob, 1024 * 1024);

  // 2) decay logits (fp32 GEMV, one wave per row)
  decay_kernel<<<2048, 256, 0, stream>>>(x, Wd, bd, ldec);

  // 3) QK = Xbf @ Wqk^T   [8192 x 2048]  (Q cols 0-1023, K cols 1024-2047)
  gemm_bt<0><<<dim3(64 * 16, 1), 256, 0, stream>>>(
      Xbf, Wqk, QK, 1024, 1024, 2048, 1024, 16, 0, nullptr, nullptr, 0, 0, 0, 0);

  // 4) VT = Wvb @ Xbf^T   [1024 x 8192]  (= V transposed, per-batch cols)
  gemm_bt<0><<<dim3(8 * 64, 1), 256, 0, stream>>>(
      Wvb, Xbf, VT, 1024, 1024, 8192, 1024, 64, 0, nullptr, nullptr, 0, 0, 0, 0);

  // 5) S_b = (Q_b K_b^T * 1/32) ∘ weights  -> bf16, upper-tri tiles only
  gemm_bt<1><<<dim3(16 * 16, 4), 256, 0, stream>>>(
      QK, QK + 1024, S, 2048, 2048, 2048, 1024, 16, 0, ldec, nullptr,
      4194304LL, 4194304LL, 4194304LL, 2048);

  // 6) R_b = S_b @ V_b   [2048 x 1024], K-loop starts at diagonal tile
  gemm_bt<0><<<dim3(16 * 8, 4), 256, 0, stream>>>(
      S, VT, R, 2048, 8192, 1024, 2048, 8, 1, nullptr, nullptr,
      4194304LL, 2048LL, 2097152LL, 0);

  // 7) out = R @ Wo^T * out_scale   [8192 x 1024] fp32
  gemm_bt<2><<<dim3(64 * 8, 1), 256, 0, stream>>>(
      R, Wob, out, 1024, 1024, 1024, 1024, 8, 0, nullptr, osc, 0, 0, 0, 0);
}